// Round 2
// baseline (260.780 us; speedup 1.0000x reference)
//
#include <hip/hip_runtime.h>

// DualModeSinkhorn, N_STREAMS=2, SINKHORN_ITER=20.
// Scan body is linear per (b,h,w): row step x[i][j] -> -x[i][1-j], col step
// y[i][j] -> -y[1-i][j]; composed = point reflection x[i][j] -> x[1-i][1-j],
// an involution. 20 (even) iters == identity => output = exp(input).
//
// R1 post-mortem: 1-elem-per-thread version was latency/dispatch bound
// (Occupancy 13.5%, 1.2 TB/s). Fix: persistent grid (2048 blocks = 8/CU),
// grid-stride with ILP=4 batched loads -> ~4KB outstanding per wave.

#define ILP 4

__global__ void __launch_bounds__(256)
exp_gs_kernel(const float4* __restrict__ in, float4* __restrict__ out, int n4) {
    int tid = blockIdx.x * blockDim.x + threadIdx.x;
    int stride = gridDim.x * blockDim.x;

    int base = tid;
    // Full ILP batches: issue ILP independent loads, then compute+store.
    for (; base + (ILP - 1) * stride < n4; base += ILP * stride) {
        float4 v[ILP];
#pragma unroll
        for (int k = 0; k < ILP; k++) {
            v[k] = in[base + k * stride];
        }
#pragma unroll
        for (int k = 0; k < ILP; k++) {
            float4 r;
            r.x = __expf(v[k].x);
            r.y = __expf(v[k].y);
            r.z = __expf(v[k].z);
            r.w = __expf(v[k].w);
            out[base + k * stride] = r;
        }
    }
    // Remainder (n4 not a multiple of ILP*stride).
    for (; base < n4; base += stride) {
        float4 v = in[base];
        float4 r;
        r.x = __expf(v.x);
        r.y = __expf(v.y);
        r.z = __expf(v.z);
        r.w = __expf(v.w);
        out[base] = r;
    }
}

__global__ void __launch_bounds__(64)
exp_tail_kernel(const float* __restrict__ in, float* __restrict__ out,
                int start, int n) {
    int idx = start + blockIdx.x * blockDim.x + threadIdx.x;
    if (idx < n) {
        out[idx] = __expf(in[idx]);
    }
}

extern "C" void kernel_launch(void* const* d_in, const int* in_sizes, int n_in,
                              void* d_out, int out_size, void* d_ws, size_t ws_size,
                              hipStream_t stream) {
    const float* in = (const float*)d_in[0];
    float* out = (float*)d_out;
    int n = out_size;                 // 16*4*768*768 = 37,748,736
    int n4 = n / 4;                   // 9,437,184 (divisible: 9437184 = 2048*256*18)

    if (n4 > 0) {
        // 8 blocks/CU * 256 CUs: fully resident, one dispatch wave.
        int blocks = 2048;
        int max_useful = (n4 + 255) / 256;
        if (blocks > max_useful) blocks = max_useful;
        exp_gs_kernel<<<blocks, 256, 0, stream>>>(
            (const float4*)in, (float4*)out, n4);
    }
    int rem = n - n4 * 4;
    if (rem > 0) {
        exp_tail_kernel<<<1, 64, 0, stream>>>(in, out, n4 * 4, n);
    }
}

// Round 3
// 257.801 us; speedup vs baseline: 1.0116x; 1.0116x over previous
//
#include <hip/hip_runtime.h>

// DualModeSinkhorn, N_STREAMS=2, SINKHORN_ITER=20.
// Scan body is linear per (b,h,w): row step x[i][j] -> -x[i][1-j], col step
// y[i][j] -> -y[1-i][j]; composed = point reflection x[i][j] -> x[1-i][1-j],
// an involution. 20 (even) iters == identity => output = exp(input).
//
// R2 post-mortem: grid-stride ILP=4 loop was per-wave latency-limited
// (4KB outstanding, vmcnt stall each iter; 2.5 TB/s). This version:
// one-shot kernel, 8 float4/thread issued as 8 independent loads up-front
// (8KB/wave in flight), contiguous 32KB per block, non-temporal stores so
// the write stream doesn't evict LLC-warm input lines.

typedef float vfloat4 __attribute__((ext_vector_type(4)));

#define VPT 8  // float4 elements per thread

__global__ void __launch_bounds__(256)
exp_oneshot_kernel(const vfloat4* __restrict__ in, vfloat4* __restrict__ out,
                   int n4) {
    const int base = blockIdx.x * (256 * VPT) + threadIdx.x;

    int idx[VPT];
    vfloat4 v[VPT];
#pragma unroll
    for (int k = 0; k < VPT; k++) {
        idx[k] = base + k * 256;
        if (idx[k] < n4) v[k] = in[idx[k]];   // 8 independent loads in flight
    }
#pragma unroll
    for (int k = 0; k < VPT; k++) {
        if (idx[k] < n4) {
            vfloat4 r;
            r.x = __expf(v[k].x);
            r.y = __expf(v[k].y);
            r.z = __expf(v[k].z);
            r.w = __expf(v[k].w);
            __builtin_nontemporal_store(r, out + idx[k]);
        }
    }
}

__global__ void __launch_bounds__(64)
exp_tail_kernel(const float* __restrict__ in, float* __restrict__ out,
                int start, int n) {
    int idx = start + blockIdx.x * blockDim.x + threadIdx.x;
    if (idx < n) {
        out[idx] = __expf(in[idx]);
    }
}

extern "C" void kernel_launch(void* const* d_in, const int* in_sizes, int n_in,
                              void* d_out, int out_size, void* d_ws, size_t ws_size,
                              hipStream_t stream) {
    const float* in = (const float*)d_in[0];
    float* out = (float*)d_out;
    int n = out_size;                 // 16*4*768*768 = 37,748,736
    int n4 = n / 4;                   // 9,437,184 = 4608 * 256 * 8 exactly

    if (n4 > 0) {
        int blocks = (n4 + 256 * VPT - 1) / (256 * VPT);   // 4608
        exp_oneshot_kernel<<<blocks, 256, 0, stream>>>(
            (const vfloat4*)in, (vfloat4*)out, n4);
    }
    int rem = n - n4 * 4;
    if (rem > 0) {
        exp_tail_kernel<<<1, 64, 0, stream>>>(in, out, n4 * 4, n);
    }
}